// Round 5
// baseline (4595.167 us; speedup 1.0000x reference)
//
#include <hip/hip_runtime.h>
#include <cstddef>

typedef float     float4_t __attribute__((ext_vector_type(4)));
typedef _Float16  half4_t  __attribute__((ext_vector_type(4)));
typedef long long ll2_t    __attribute__((ext_vector_type(2)));

#define T_STEPS 128
#define BATCH   2048
#define DATA    64
#define DIM     128
#define WIDTH   256
#define SUBSTEPS 4
#define BT      4              // real batch cols per WG (N=16 padded)
#define NWG     (BATCH / BT)   // 512 WGs -> breadth-first gives 2 WGs/CU
#define NTHREADS 256           // 4 waves/WG; 2 WGs/CU -> 2 waves/SIMD, DECOUPLED barriers
#define SY8 144                // Y row stride bytes (128 fp8 + 16 pad)
#define SH8 272                // H row stride bytes (256 fp8 + 16 pad)
#define WSCALE 16.0f           // weights packed as fp8(16*W); result scaled by 1/16
#define IWS (1.0f / 16.0f)

#define MFMA8(A, B, C) __builtin_amdgcn_mfma_f32_16x16x32_fp8_fp8((A), (B), (C), 0, 0, 0)

struct st2 { float4_t lo, hi; };

__global__ __launch_bounds__(NTHREADS, 2)
void anode_kernel(const float* __restrict__ ts, const float* __restrict__ y0,
                  const float* __restrict__ W1, const float* __restrict__ b1,
                  const float* __restrict__ W2, const float* __restrict__ b2,
                  const float* __restrict__ W3, const float* __restrict__ b3,
                  float* __restrict__ out)
{
  // All-fp8 activation buffers, fragment-major per batch-row n:
  //  Y : byte(n,k) = n*SY8 + ((k>>3)&3)*32 + (k>>5)*8 + (k&7)   (K=128)
  //  H : byte(n,k) = n*SH8 + ((k>>3)&3)*64 + (k>>5)*8 + (k&7)   (K=256)
  // -> one lane's K=32 fragments are 8B-contiguous; 2 frags per b128 read.
  __shared__ __align__(16) char Yb[16 * SY8];
  __shared__ __align__(16) char H1[16 * SH8];
  __shared__ __align__(16) char H2[16 * SH8];

  const int tid  = threadIdx.x;
  const int wave = tid >> 6;    // 0..3
  const int lane = tid & 63;
  const int n    = lane & 15;   // MFMA N index; real cols are n<4
  const int quad = lane >> 4;   // 0..3
  const int bbase = blockIdx.x * BT;

  // fp8 (OCP e4m3) pack of 8 scaled floats.
  auto qpack = [](const float* w, float s) -> long long {
    unsigned int lo = 0, hi = 0;
    lo = __builtin_amdgcn_cvt_pk_fp8_f32(w[0]*s, w[1]*s, lo, false);
    lo = __builtin_amdgcn_cvt_pk_fp8_f32(w[2]*s, w[3]*s, lo, true);
    hi = __builtin_amdgcn_cvt_pk_fp8_f32(w[4]*s, w[5]*s, hi, false);
    hi = __builtin_amdgcn_cvt_pk_fp8_f32(w[6]*s, w[7]*s, hi, true);
    return (long long)((unsigned long long)lo | ((unsigned long long)hi << 32));
  };

  // ---- Weights in registers, fp8 x16, A-layout:
  //   lane holds A[m = Mbase + n][k = kt*32 + quad*8 + j]
  // L1/L2: wave owns M rows [64w, 64w+64) (mt=4). L3: rows [32w,32w+32) (jt=2).
  long long a1[4][4];   // W1 256x128
  long long a2[4][8];   // W2 256x256
  long long a3[2][8];   // W3 128x256
  half4_t bh1[4], bh2[4], bh3[2];   // biases, pre-scaled x16, fp16 storage

  #pragma unroll
  for (int mt = 0; mt < 4; ++mt) {
    const int m = wave * 64 + mt * 16 + n;
    #pragma unroll
    for (int kt = 0; kt < 4; ++kt) {
      float w[8];
      #pragma unroll
      for (int j = 0; j < 8; ++j) w[j] = W1[(size_t)m * DIM + kt * 32 + quad * 8 + j];
      a1[mt][kt] = qpack(w, WSCALE);
    }
    #pragma unroll
    for (int kt = 0; kt < 8; ++kt) {
      float w[8];
      #pragma unroll
      for (int j = 0; j < 8; ++j) w[j] = W2[(size_t)m * WIDTH + kt * 32 + quad * 8 + j];
      a2[mt][kt] = qpack(w, WSCALE);
    }
    const int bm = wave * 64 + mt * 16 + quad * 4;
    bh1[mt] = half4_t{(_Float16)(WSCALE*b1[bm]),   (_Float16)(WSCALE*b1[bm+1]),
                      (_Float16)(WSCALE*b1[bm+2]), (_Float16)(WSCALE*b1[bm+3])};
    bh2[mt] = half4_t{(_Float16)(WSCALE*b2[bm]),   (_Float16)(WSCALE*b2[bm+1]),
                      (_Float16)(WSCALE*b2[bm+2]), (_Float16)(WSCALE*b2[bm+3])};
  }
  #pragma unroll
  for (int jt = 0; jt < 2; ++jt) {
    const int m3 = wave * 32 + jt * 16 + n;
    #pragma unroll
    for (int kt = 0; kt < 8; ++kt) {
      float w[8];
      #pragma unroll
      for (int j = 0; j < 8; ++j) w[j] = W3[(size_t)m3 * WIDTH + kt * 32 + quad * 8 + j];
      a3[jt][kt] = qpack(w, WSCALE);
    }
    const int bm = wave * 32 + jt * 16 + quad * 4;
    bh3[jt] = half4_t{(_Float16)(WSCALE*b3[bm]),   (_Float16)(WSCALE*b3[bm+1]),
                      (_Float16)(WSCALE*b3[bm+2]), (_Float16)(WSCALE*b3[bm+3])};
  }

  // LDS pointers
  const char* rdY  = Yb + n * SY8 + quad * 32;   // 2x b128 (+0,+16)
  const char* rdH1 = H1 + n * SH8 + quad * 64;   // 4x b128
  const char* rdH2 = H2 + n * SH8 + quad * 64;
  auto hwpY = [&](int m) -> char* {
    return Yb + n * SY8 + ((m >> 3) & 3) * 32 + (m >> 5) * 8 + (m & 7);
  };
  auto hwpH = [&](char* base, int m) -> char* {
    return base + n * SH8 + ((m >> 3) & 3) * 64 + (m >> 5) * 8 + (m & 7);
  };
  char* wrY0 = hwpY(32 * wave + quad * 4);
  char* wrY1 = hwpY(32 * wave + 16 + quad * 4);
  char* wrH1p[4], *wrH2p[4];
  #pragma unroll
  for (int mt = 0; mt < 4; ++mt) {
    wrH1p[mt] = hwpH(H1, 64 * wave + 16 * mt + quad * 4);
    wrH2p[mt] = hwpH(H2, 64 * wave + 16 * mt + quad * 4);
  }

  auto cvtb = [](half4_t b) -> float4_t {
    return float4_t{(float)b[0], (float)b[1], (float)b[2], (float)b[3]};
  };
  auto packrelu = [](float4_t v) -> unsigned int {
    v[0]=fmaxf(v[0]*IWS,0.f); v[1]=fmaxf(v[1]*IWS,0.f);
    v[2]=fmaxf(v[2]*IWS,0.f); v[3]=fmaxf(v[3]*IWS,0.f);
    unsigned int p = 0;
    p = __builtin_amdgcn_cvt_pk_fp8_f32(v[0], v[1], p, false);
    p = __builtin_amdgcn_cvt_pk_fp8_f32(v[2], v[3], p, true);
    return p;
  };
  auto pack4 = [](float4_t v) -> unsigned int {
    unsigned int p = 0;
    p = __builtin_amdgcn_cvt_pk_fp8_f32(v[0], v[1], p, false);
    p = __builtin_amdgcn_cvt_pk_fp8_f32(v[2], v[3], p, true);
    return p;
  };

  // f(y): lane owns state dims d = 32*wave + 16*j + quad*4 + r  (j=0,1)
  auto feval = [&](st2 yin) -> st2 {
    *(unsigned int*)wrY0 = pack4(yin.lo);
    *(unsigned int*)wrY1 = pack4(yin.hi);
    __syncthreads();

    // L1: 256x128 @ 128x16, 2 b128 B-reads, 4 chains of depth 4
    float4_t c0 = cvtb(bh1[0]), c1 = cvtb(bh1[1]), c2 = cvtb(bh1[2]), c3 = cvtb(bh1[3]);
    {
      ll2_t p0 = *(const ll2_t*)(rdY);        // frags kt0, kt1
      ll2_t p1 = *(const ll2_t*)(rdY + 16);   // frags kt2, kt3
      c0 = MFMA8(a1[0][0], p0[0], c0); c1 = MFMA8(a1[1][0], p0[0], c1);
      c2 = MFMA8(a1[2][0], p0[0], c2); c3 = MFMA8(a1[3][0], p0[0], c3);
      c0 = MFMA8(a1[0][1], p0[1], c0); c1 = MFMA8(a1[1][1], p0[1], c1);
      c2 = MFMA8(a1[2][1], p0[1], c2); c3 = MFMA8(a1[3][1], p0[1], c3);
      c0 = MFMA8(a1[0][2], p1[0], c0); c1 = MFMA8(a1[1][2], p1[0], c1);
      c2 = MFMA8(a1[2][2], p1[0], c2); c3 = MFMA8(a1[3][2], p1[0], c3);
      c0 = MFMA8(a1[0][3], p1[1], c0); c1 = MFMA8(a1[1][3], p1[1], c1);
      c2 = MFMA8(a1[2][3], p1[1], c2); c3 = MFMA8(a1[3][3], p1[1], c3);
    }
    *(unsigned int*)wrH1p[0] = packrelu(c0);
    *(unsigned int*)wrH1p[1] = packrelu(c1);
    *(unsigned int*)wrH1p[2] = packrelu(c2);
    *(unsigned int*)wrH1p[3] = packrelu(c3);
    __syncthreads();

    // L2: 256x256 @ 256x16, 4 b128 B-reads, 4 chains of depth 8
    float4_t d0 = cvtb(bh2[0]), d1 = cvtb(bh2[1]), d2 = cvtb(bh2[2]), d3 = cvtb(bh2[3]);
    {
      ll2_t p0 = *(const ll2_t*)(rdH1);
      ll2_t p1 = *(const ll2_t*)(rdH1 + 16);
      ll2_t p2 = *(const ll2_t*)(rdH1 + 32);
      ll2_t p3 = *(const ll2_t*)(rdH1 + 48);
      #pragma unroll
      for (int h = 0; h < 2; ++h) {
        long long f0 = h ? p0[1] : p0[0], f1 = h ? p1[1] : p1[0];
        long long f2 = h ? p2[1] : p2[0], f3 = h ? p3[1] : p3[0];
        d0 = MFMA8(a2[0][h], f0, d0);     d1 = MFMA8(a2[1][h], f0, d1);
        d2 = MFMA8(a2[2][h], f0, d2);     d3 = MFMA8(a2[3][h], f0, d3);
        d0 = MFMA8(a2[0][2+h], f1, d0);   d1 = MFMA8(a2[1][2+h], f1, d1);
        d2 = MFMA8(a2[2][2+h], f1, d2);   d3 = MFMA8(a2[3][2+h], f1, d3);
        d0 = MFMA8(a2[0][4+h], f2, d0);   d1 = MFMA8(a2[1][4+h], f2, d1);
        d2 = MFMA8(a2[2][4+h], f2, d2);   d3 = MFMA8(a2[3][4+h], f2, d3);
        d0 = MFMA8(a2[0][6+h], f3, d0);   d1 = MFMA8(a2[1][6+h], f3, d1);
        d2 = MFMA8(a2[2][6+h], f3, d2);   d3 = MFMA8(a2[3][6+h], f3, d3);
      }
    }
    *(unsigned int*)wrH2p[0] = packrelu(d0);
    *(unsigned int*)wrH2p[1] = packrelu(d1);
    *(unsigned int*)wrH2p[2] = packrelu(d2);
    *(unsigned int*)wrH2p[3] = packrelu(d3);
    __syncthreads();

    // L3: 128x256 @ 256x16 (linear), 4 b128 B-reads, 2 chains of depth 8
    float4_t e0 = cvtb(bh3[0]), e1 = cvtb(bh3[1]);
    {
      ll2_t p0 = *(const ll2_t*)(rdH2);
      ll2_t p1 = *(const ll2_t*)(rdH2 + 16);
      ll2_t p2 = *(const ll2_t*)(rdH2 + 32);
      ll2_t p3 = *(const ll2_t*)(rdH2 + 48);
      #pragma unroll
      for (int h = 0; h < 2; ++h) {
        long long f0 = h ? p0[1] : p0[0], f1 = h ? p1[1] : p1[0];
        long long f2 = h ? p2[1] : p2[0], f3 = h ? p3[1] : p3[0];
        e0 = MFMA8(a3[0][h], f0, e0);     e1 = MFMA8(a3[1][h], f0, e1);
        e0 = MFMA8(a3[0][2+h], f1, e0);   e1 = MFMA8(a3[1][2+h], f1, e1);
        e0 = MFMA8(a3[0][4+h], f2, e0);   e1 = MFMA8(a3[1][4+h], f2, e1);
        e0 = MFMA8(a3[0][6+h], f3, e0);   e1 = MFMA8(a3[1][6+h], f3, e1);
      }
    }
    return { IWS * e0, IWS * e1 };
  };

  // ---- state init (clamp row for padded cols n>=BT) ----
  const int row = (bbase + n) < BATCH ? (bbase + n) : (BATCH - 1);
  st2 y;
  y.lo = *(const float4_t*)(y0 + (size_t)row * DIM + wave * 32 + quad * 4);
  y.hi = *(const float4_t*)(y0 + (size_t)row * DIM + wave * 32 + 16 + quad * 4);

  if (wave < 2 && n < BT) {
    float* o = out + (size_t)(bbase + n) * DATA;
    *(float4_t*)(o + wave * 32 + quad * 4) = y.lo;
    *(float4_t*)(o + wave * 32 + 16 + quad * 4) = y.hi;
  }
  if (blockIdx.x == 0 && tid == 0)
    out[(size_t)T_STEPS * BATCH * DATA] = (float)((T_STEPS - 1) * SUBSTEPS); // 508.0f

  const float A31=(float)(3.0/40.0),      A32=(float)(9.0/40.0);
  const float A41=(float)(44.0/45.0),     A42=(float)(-56.0/15.0),    A43=(float)(32.0/9.0);
  const float A51=(float)(19372.0/6561.0),A52=(float)(-25360.0/2187.0),
              A53=(float)(64448.0/6561.0),A54=(float)(-212.0/729.0);
  const float A61=(float)(9017.0/3168.0), A62=(float)(-355.0/33.0),
              A63=(float)(46732.0/5247.0),A64=(float)(49.0/176.0),    A65=(float)(-5103.0/18656.0);
  const float B1=(float)(35.0/384.0),     B3=(float)(500.0/1113.0),   B4=(float)(125.0/192.0),
              B5=(float)(-2187.0/6784.0), B6=(float)(11.0/84.0);

  for (int t = 0; t < T_STEPS - 1; ++t) {
    const float dt = (ts[t + 1] - ts[t]) * (1.0f / SUBSTEPS);
    for (int s = 0; s < SUBSTEPS; ++s) {
      st2 k1 = feval(y);
      st2 k2 = feval({ y.lo + (dt*0.2f)*k1.lo, y.hi + (dt*0.2f)*k1.hi });
      st2 k3 = feval({ y.lo + dt*(A31*k1.lo + A32*k2.lo),
                       y.hi + dt*(A31*k1.hi + A32*k2.hi) });
      st2 k4 = feval({ y.lo + dt*(A41*k1.lo + A42*k2.lo + A43*k3.lo),
                       y.hi + dt*(A41*k1.hi + A42*k2.hi + A43*k3.hi) });
      st2 k5 = feval({ y.lo + dt*(A51*k1.lo + A52*k2.lo + A53*k3.lo + A54*k4.lo),
                       y.hi + dt*(A51*k1.hi + A52*k2.hi + A53*k3.hi + A54*k4.hi) });
      st2 a6 = { y.lo + dt*(A61*k1.lo + A62*k2.lo + A63*k3.lo + A64*k4.lo + A65*k5.lo),
                 y.hi + dt*(A61*k1.hi + A62*k2.hi + A63*k3.hi + A64*k4.hi + A65*k5.hi) };
      // fold k1..k5 into y BEFORE stage 6 so they die (peak-VGPR control)
      y.lo = y.lo + dt*(B1*k1.lo + B3*k3.lo + B4*k4.lo + B5*k5.lo);
      y.hi = y.hi + dt*(B1*k1.hi + B3*k3.hi + B4*k4.hi + B5*k5.hi);
      st2 k6 = feval(a6);
      y.lo = y.lo + (dt*B6)*k6.lo;
      y.hi = y.hi + (dt*B6)*k6.hi;
    }
    if (wave < 2 && n < BT) {
      float* o = out + (size_t)(t + 1) * (BATCH * DATA) + (size_t)(bbase + n) * DATA;
      *(float4_t*)(o + wave * 32 + quad * 4) = y.lo;
      *(float4_t*)(o + wave * 32 + 16 + quad * 4) = y.hi;
    }
  }
}

extern "C" void kernel_launch(void* const* d_in, const int* in_sizes, int n_in,
                              void* d_out, int out_size, void* d_ws, size_t ws_size,
                              hipStream_t stream) {
  (void)in_sizes; (void)n_in; (void)out_size; (void)d_ws; (void)ws_size;
  const float* ts = (const float*)d_in[0];
  const float* y0 = (const float*)d_in[1];
  const float* W1 = (const float*)d_in[2];
  const float* b1 = (const float*)d_in[3];
  const float* W2 = (const float*)d_in[4];
  const float* b2 = (const float*)d_in[5];
  const float* W3 = (const float*)d_in[6];
  const float* b3 = (const float*)d_in[7];
  anode_kernel<<<dim3(NWG), dim3(NTHREADS), 0, stream>>>(
      ts, y0, W1, b1, W2, b2, W3, b3, (float*)d_out);
}